// Round 4
// baseline (422.056 us; speedup 1.0000x reference)
//
#include <hip/hip_runtime.h>
#include <stdint.h>
#include <stddef.h>

// FCBlock fused kernel v4 for MI355X (gfx950).
// Network: L=3, H=512, D=3, N=65536.
// v4: 2-kt-deep rotating B prefetch (3 buffers), cross-GEMM B preload chain
// (epilogues hide pipeline refill), wave-split conflict-free s-dot.
// 512 thr / 8 waves per WG; wave owns 64 rows x 64 cols; B direct from L2 in
// MFMA-fragment order; u/zz live in LDS across the whole network.

typedef float  f32x4 __attribute__((ext_vector_type(4)));
typedef __bf16 bf16x8 __attribute__((ext_vector_type(8)));

// Activation element index inside a 64-row x 512-col bf16 buffer stored as
// MFMA fragment blocks: [kt=k>>5][rt=row>>4][lane=(row&15)|(((k>>3)&3)<<4)][e=k&7]
__device__ __forceinline__ int act_idx(int row, int k){
  return ((k>>5)<<11) | ((row>>4)<<9) | (((k>>3)&3)<<7) | ((row&15)<<3) | (k&7);
}

// ---------------------------------------------------------------------------
// Weight prep: convert 9 fp32 [512][512] matrices (k-major) to bf16 in
// fragment-block layout: per matrix: [kt(16)][jt(32)][lane(64)][e(8)] shorts.
// Matrix order m: 0..2 Wzuu[0..2], 3..4 Wzzu[0..1], 5..6 Wzu[0..1], 7..8 Wu[0..1]
// ---------------------------------------------------------------------------
__global__ void prep_weights(const float* __restrict__ Wzuu, const float* __restrict__ Wzzu,
                             const float* __restrict__ Wzu,  const float* __restrict__ Wu,
                             __bf16* __restrict__ Wb)
{
  int gid = blockIdx.x * 256 + threadIdx.x;   // [0, 9*512*128)
  int m   = gid >> 16;
  int rem = gid & 65535;
  int k   = rem >> 7;
  int j0  = (rem & 127) << 2;
  const float* src;
  if      (m < 3) src = Wzuu + (size_t)m     * 262144;
  else if (m < 5) src = Wzzu + (size_t)(m-3) * 262144;
  else if (m < 7) src = Wzu  + (size_t)(m-5) * 262144;
  else            src = Wu   + (size_t)(m-7) * 262144;
  const float4 v = *(const float4*)(src + k*512 + j0);
  const int base = m << 18;   // m * 262144 elements
  #pragma unroll
  for (int e = 0; e < 4; ++e){
    const int j = j0 + e;
    const float x = (e==0) ? v.x : (e==1) ? v.y : (e==2) ? v.z : v.w;
    const int off = ((k>>5)<<14) | ((j>>4)<<9)
                  | ((((j&15) | (((k>>3)&3)<<4)))<<3) | (k&7);
    Wb[base + off] = (__bf16)x;
  }
}

// ---------------------------------------------------------------------------
// 64x64 (per wave) += A[64x512] @ W[512x512] restricted to this wave's cols.
// A from LDS (fragment layout, double-buffered), B from global/L2 in fragment
// order with 2-kt-deep rotating prefetch (3 buffers). On entry bpre[] holds
// this stream's kt=0,1 fragments; on exit bpre[] holds wb_next's kt=0,1.
// ---------------------------------------------------------------------------
__device__ __forceinline__ void gemm_acc(const __bf16* __restrict__ a_lds,
                                         const __bf16* __restrict__ wb,
                                         const __bf16* __restrict__ wb_next,
                                         bf16x8 bpre[2][4],
                                         f32x4 acc[4][4],
                                         int wv, int lane)
{
  const int woff = ((wv<<2)<<9) + (lane<<3);
  const __bf16* wp = wb + woff;
  bf16x8 b[3][4];
  bf16x8 a[2][4];
  #pragma unroll
  for (int jt = 0; jt < 4; ++jt){ b[0][jt] = bpre[0][jt]; b[1][jt] = bpre[1][jt]; }
  #pragma unroll
  for (int rt = 0; rt < 4; ++rt)
    a[0][rt] = *(const bf16x8*)(a_lds + (rt<<9) + (lane<<3));
  #pragma unroll
  for (int kt = 0; kt < 16; ++kt){
    if (kt < 14){
      // issue kt+2 B loads (2-deep: covers L2 latency + queueing)
      #pragma unroll
      for (int jt = 0; jt < 4; ++jt)
        b[(kt+2)%3][jt] = *(const bf16x8*)(wp + ((kt+2)<<14) + (jt<<9));
    } else {
      // tail: preload NEXT stream's kt=0,1 — epilogue/barriers hide this
      #pragma unroll
      for (int jt = 0; jt < 4; ++jt)
        bpre[kt-14][jt] = *(const bf16x8*)(wb_next + woff + ((kt-14)<<14) + (jt<<9));
    }
    if (kt < 15){
      #pragma unroll
      for (int rt = 0; rt < 4; ++rt)
        a[(kt+1)&1][rt] = *(const bf16x8*)(a_lds + ((kt+1)<<11) + (rt<<9) + (lane<<3));
    }
    #pragma unroll
    for (int jt = 0; jt < 4; ++jt)
      #pragma unroll
      for (int rt = 0; rt < 4; ++rt)
        acc[rt][jt] = __builtin_amdgcn_mfma_f32_16x16x32_bf16(a[kt&1][rt], b[kt%3][jt], acc[rt][jt], 0, 0, 0);
  }
}

// ---------------------------------------------------------------------------
// Fused network kernel: 1024 blocks x 512 threads; block owns rows n0..n0+63.
// ---------------------------------------------------------------------------
__global__ __launch_bounds__(512, 2) void fc_fused(
    const float* __restrict__ coords,
    const __bf16* __restrict__ Wb,
    const float* __restrict__ Wu0,  const float* __restrict__ bu0,
    const float* __restrict__ bu,
    const float* __restrict__ bzuu,
    const float* __restrict__ Wzzu_last,
    const float* __restrict__ Wyuu0, const float* __restrict__ byuu0,
    const float* __restrict__ Wyuu,  const float* __restrict__ byuu,
    const float* __restrict__ Wzyu,  const float* __restrict__ Wzyu_last,
    const float* __restrict__ Wzu0,  const float* __restrict__ bzu0,
    const float* __restrict__ bzu,
    const float* __restrict__ Wzu_last, const float* __restrict__ bzu_last,
    const float* __restrict__ p, const float* __restrict__ pu, const float* __restrict__ pzu,
    float* __restrict__ out)
{
  __shared__ __align__(16) __bf16 u_lds [32768];  // 64KB: u[64][512]
  __shared__ __align__(16) __bf16 zz_lds[32768];  // 64KB: z / zz [64][512]
  __shared__ float sp_lds[2][64];                 // s-dot partials (two k-halves)

  const int tid  = threadIdx.x;
  const int lane = tid & 63;
  const int wv   = tid >> 6;        // 0..7
  const int n0   = blockIdx.x << 6;

  const float P  = 10.f * p[0];
  const float PU = 10.f * pu[0];
  const float PZ = 10.f * pzu[0];

  const float y_l = coords[(size_t)(n0 + lane)*4 + 3];   // lane L holds y[row L]

  // preload first GEMM stream's (Wzuu[0]) kt=0,1 B fragments
  bf16x8 bpre[2][4];
  {
    const int woff = ((wv<<2)<<9) + (lane<<3);
    #pragma unroll
    for (int s2 = 0; s2 < 2; ++s2)
      #pragma unroll
      for (int jt = 0; jt < 4; ++jt)
        bpre[s2][jt] = *(const bf16x8*)(Wb + woff + (s2<<14) + (jt<<9));
  }

  // -------- layer 0: z0, u0 (D=3 input dots, direct compute) --------
  for (int s = tid; s < 4096; s += 512){
    const int row = s >> 6;
    const int k0  = (s & 63) << 3;
    const float* c = coords + (size_t)(n0 + row)*4;
    const float c0 = c[0], c1 = c[1], c2 = c[2], yy = c[3];
    const float s0 = c0*Wyuu0[0] + c1*Wyuu0[1] + c2*Wyuu0[2] + byuu0[0];
    bf16x8 pu8, pz8;
    #pragma unroll
    for (int e = 0; e < 8; ++e){
      const int k = k0 + e;
      const float uv = c0*Wu0[k]  + c1*Wu0[512+k]  + c2*Wu0[1024+k]  + bu0[k];
      pu8[e] = (__bf16)fmaxf(PU*uv, 0.f);
      const float zv = c0*Wzu0[k] + c1*Wzu0[512+k] + c2*Wzu0[1024+k] + bzu0[k]
                     + yy*s0*Wzyu[k];            // Wzyu[0][:, k]
      pz8[e] = (__bf16)fmaxf(P*zv, 0.f);
    }
    *(bf16x8*)(u_lds  + act_idx(row, k0)) = pu8;
    *(bf16x8*)(zz_lds + act_idx(row, k0)) = pz8;
  }
  __syncthreads();

  f32x4 acc[4][4];

  for (int it = 0; it < 3; ++it){
    const __bf16* w_p1 = Wb + ((size_t)it     << 18);   // Wzuu[it]
    const __bf16* w_zz = Wb + ((size_t)(3+it) << 18);   // Wzzu[it]
    const __bf16* w_zu = Wb + ((size_t)(5+it) << 18);   // Wzu[it]
    const __bf16* w_u  = Wb + ((size_t)(7+it) << 18);   // Wu[it]
    const __bf16* w_n1 = (it < 2) ? w_zz : w_p1;        // after phase1
    const __bf16* w_nx = (it < 2) ? (Wb + ((size_t)(it+1) << 18)) : w_p1;

    // ---- s-dot: sp[kh][row] = partial of u[row,:] . Wyuu[it] ----
    // wave wv: row-group rt=wv&3, k-half kh=wv>>2; conflict-free frag reads.
    {
      const float* wc = Wyuu + (it<<9);
      const int rt = wv & 3;
      const int kh = wv >> 2;
      float pp = 0.f;
      #pragma unroll
      for (int t = 0; t < 8; ++t){
        const int kt = (kh<<3) + t;
        const int k0 = (kt<<5) + ((lane>>4)<<3);
        bf16x8 v = *(const bf16x8*)(u_lds + (kt<<11) + (rt<<9) + (lane<<3));
        const float4 w0 = *(const float4*)(wc + k0);
        const float4 w1 = *(const float4*)(wc + k0 + 4);
        pp += (float)v[0]*w0.x + (float)v[1]*w0.y + (float)v[2]*w0.z + (float)v[3]*w0.w
            + (float)v[4]*w1.x + (float)v[5]*w1.y + (float)v[6]*w1.z + (float)v[7]*w1.w;
      }
      pp += __shfl_xor(pp, 16);
      pp += __shfl_xor(pp, 32);
      if (lane < 16) sp_lds[kh][(rt<<4) + lane] = pp;
    }

    // ---- phase 1: t = u @ Wzuu[it];  zz = z * relu(PZ*(t + bzuu[it])) ----
    #pragma unroll
    for (int rt = 0; rt < 4; ++rt)
      #pragma unroll
      for (int jt = 0; jt < 4; ++jt)
        acc[rt][jt] = (f32x4){0.f,0.f,0.f,0.f};
    gemm_acc(u_lds, w_p1, w_n1, bpre, acc, wv, lane);
    #pragma unroll
    for (int jt = 0; jt < 4; ++jt){
      const int col = (wv<<6) + (jt<<4) + (lane & 15);
      const float bz = bzuu[(it<<9) + col];
      #pragma unroll
      for (int rt = 0; rt < 4; ++rt){
        #pragma unroll
        for (int rr = 0; rr < 4; ++rr){
          const int row = (rt<<4) + ((lane>>4)<<2) + rr;
          const int idx = act_idx(row, col);
          const float zold = (float)zz_lds[idx];    // element owned by this thread
          const float t    = acc[rt][jt][rr] + bz;
          zz_lds[idx] = (__bf16)(zold * fmaxf(PZ*t, 0.f));
        }
      }
    }
    __syncthreads();   // zz + sp fully written before reads

    if (it < 2){
      // ---- phase 2a: z = relu(P*(zz@Wzzu + u@Wzu + bzu + y*s*Wzyu[it+1])) ----
      #pragma unroll
      for (int rt = 0; rt < 4; ++rt)
        #pragma unroll
        for (int jt = 0; jt < 4; ++jt)
          acc[rt][jt] = (f32x4){0.f,0.f,0.f,0.f};
      gemm_acc(zz_lds, w_zz, w_zu, bpre, acc, wv, lane);
      gemm_acc(u_lds,  w_zu, w_u,  bpre, acc, wv, lane);
      __syncthreads();   // all waves done reading zz before epilogue overwrites it

      const float by_it = byuu[it];
      float ysr[4][4];
      #pragma unroll
      for (int rt = 0; rt < 4; ++rt)
        #pragma unroll
        for (int rr = 0; rr < 4; ++rr){
          const int row = (rt<<4) + ((lane>>4)<<2) + rr;
          ysr[rt][rr] = __shfl(y_l, row) * (sp_lds[0][row] + sp_lds[1][row] + by_it);
        }
      #pragma unroll
      for (int jt = 0; jt < 4; ++jt){
        const int col = (wv<<6) + (jt<<4) + (lane & 15);
        const float bz  = bzu[(it<<9) + col];
        const float wzy = Wzyu[((it+1)<<9) + col];
        #pragma unroll
        for (int rt = 0; rt < 4; ++rt){
          #pragma unroll
          for (int rr = 0; rr < 4; ++rr){
            const int row = (rt<<4) + ((lane>>4)<<2) + rr;
            const float zn = acc[rt][jt][rr] + bz + ysr[rt][rr]*wzy;
            zz_lds[act_idx(row, col)] = (__bf16)fmaxf(P*zn, 0.f);
          }
        }
      }

      // ---- phase 2b: u = relu(PU*(u @ Wu[it] + bu[it])) ----
      #pragma unroll
      for (int rt = 0; rt < 4; ++rt)
        #pragma unroll
        for (int jt = 0; jt < 4; ++jt)
          acc[rt][jt] = (f32x4){0.f,0.f,0.f,0.f};
      gemm_acc(u_lds, w_u, w_nx, bpre, acc, wv, lane);
      __syncthreads();   // all waves done reading u before epilogue overwrites it
      #pragma unroll
      for (int jt = 0; jt < 4; ++jt){
        const int col = (wv<<6) + (jt<<4) + (lane & 15);
        const float bb = bu[(it<<9) + col];
        #pragma unroll
        for (int rt = 0; rt < 4; ++rt){
          #pragma unroll
          for (int rr = 0; rr < 4; ++rr){
            const int row = (rt<<4) + ((lane>>4)<<2) + rr;
            u_lds[act_idx(row, col)] = (__bf16)fmaxf(PU*(acc[rt][jt][rr] + bb), 0.f);
          }
        }
      }
      __syncthreads();   // u/z writes visible before next iteration's reads
    } else {
      // ---- final: out = zz.Wzzu_last + u.Wzu_last + bzu_last + y*s*Wzyu_last ----
      const int row = tid >> 3;     // 0..63
      const int q   = tid & 7;
      float av = 0.f, au = 0.f;
      for (int kb = q*8; kb < q*8 + 8; ++kb){
        const int k0 = kb << 3;
        bf16x8 vz = *(const bf16x8*)(zz_lds + act_idx(row, k0));
        bf16x8 vu = *(const bf16x8*)(u_lds  + act_idx(row, k0));
        #pragma unroll
        for (int e = 0; e < 8; ++e){
          av += (float)vz[e] * Wzzu_last[k0+e];
          au += (float)vu[e] * Wzu_last [k0+e];
        }
      }
      float tot = av + au;
      tot += __shfl_xor(tot, 1);
      tot += __shfl_xor(tot, 2);
      tot += __shfl_xor(tot, 4);
      const float sv = sp_lds[0][row] + sp_lds[1][row] + byuu[2];
      const float yv = __shfl(y_l, row & 63);
      if (q == 0)
        out[n0 + row] = tot + bzu_last[0] + yv*sv*Wzyu_last[0];
    }
  }
}

// ---------------------------------------------------------------------------
extern "C" void kernel_launch(void* const* d_in, const int* in_sizes, int n_in,
                              void* d_out, int out_size, void* d_ws, size_t ws_size,
                              hipStream_t stream)
{
  const float* coords    = (const float*)d_in[0];
  const float* Wu0       = (const float*)d_in[1];
  const float* bu0       = (const float*)d_in[2];
  const float* Wu        = (const float*)d_in[3];
  const float* bu        = (const float*)d_in[4];
  const float* Wzuu      = (const float*)d_in[5];
  const float* bzuu      = (const float*)d_in[6];
  const float* Wzzu      = (const float*)d_in[7];
  const float* Wzzu_last = (const float*)d_in[8];
  const float* Wyuu0     = (const float*)d_in[9];
  const float* byuu0     = (const float*)d_in[10];
  const float* Wyuu      = (const float*)d_in[11];
  const float* byuu      = (const float*)d_in[12];
  const float* Wzyu      = (const float*)d_in[13];
  const float* Wzyu_last = (const float*)d_in[14];
  const float* Wzu0      = (const float*)d_in[15];
  const float* bzu0      = (const float*)d_in[16];
  const float* Wzu       = (const float*)d_in[17];
  const float* bzu       = (const float*)d_in[18];
  const float* Wzu_last  = (const float*)d_in[19];
  const float* bzu_last  = (const float*)d_in[20];
  const float* p         = (const float*)d_in[21];
  const float* pu        = (const float*)d_in[22];
  const float* pzu       = (const float*)d_in[23];

  __bf16* Wb = (__bf16*)d_ws;   // 9 * 512KB = 4.5 MB bf16 fragment-block weights

  prep_weights<<<2304, 256, 0, stream>>>(Wzuu, Wzzu, Wzu, Wu, Wb);

  fc_fused<<<1024, 512, 0, stream>>>(
      coords, Wb,
      Wu0, bu0, bu, bzuu, Wzzu_last,
      Wyuu0, byuu0, Wyuu, byuu, Wzyu, Wzyu_last,
      Wzu0, bzu0, bzu, Wzu_last, bzu_last,
      p, pu, pzu,
      (float*)d_out);
}

// Round 5
// 349.180 us; speedup vs baseline: 1.2087x; 1.2087x over previous
//
#include <hip/hip_runtime.h>
#include <stdint.h>
#include <stddef.h>

// FCBlock fused kernel v5 for MI355X (gfx950).
// Network: L=3, H=512, D=3, N=65536.
// v5: spill-free depth-4 rotating B prefetch (all register arrays statically
// indexed after full unroll; no arrays passed across call boundaries).
// 512 thr / 8 waves per WG; wave owns 64 rows x 64 cols; B direct from L2 in
// MFMA-fragment order; u/zz live in LDS across the whole network.

typedef float  f32x4 __attribute__((ext_vector_type(4)));
typedef __bf16 bf16x8 __attribute__((ext_vector_type(8)));

// Activation element index inside a 64-row x 512-col bf16 buffer stored as
// MFMA fragment blocks: [kt=k>>5][rt=row>>4][lane=(row&15)|(((k>>3)&3)<<4)][e=k&7]
__device__ __forceinline__ int act_idx(int row, int k){
  return ((k>>5)<<11) | ((row>>4)<<9) | (((k>>3)&3)<<7) | ((row&15)<<3) | (k&7);
}

// ---------------------------------------------------------------------------
// Weight prep: convert 9 fp32 [512][512] matrices (k-major) to bf16 in
// fragment-block layout: per matrix: [kt(16)][jt(32)][lane(64)][e(8)] shorts.
// Matrix order m: 0..2 Wzuu[0..2], 3..4 Wzzu[0..1], 5..6 Wzu[0..1], 7..8 Wu[0..1]
// ---------------------------------------------------------------------------
__global__ void prep_weights(const float* __restrict__ Wzuu, const float* __restrict__ Wzzu,
                             const float* __restrict__ Wzu,  const float* __restrict__ Wu,
                             __bf16* __restrict__ Wb)
{
  int gid = blockIdx.x * 256 + threadIdx.x;   // [0, 9*512*128)
  int m   = gid >> 16;
  int rem = gid & 65535;
  int k   = rem >> 7;
  int j0  = (rem & 127) << 2;
  const float* src;
  if      (m < 3) src = Wzuu + (size_t)m     * 262144;
  else if (m < 5) src = Wzzu + (size_t)(m-3) * 262144;
  else if (m < 7) src = Wzu  + (size_t)(m-5) * 262144;
  else            src = Wu   + (size_t)(m-7) * 262144;
  const float4 v = *(const float4*)(src + k*512 + j0);
  const int base = m << 18;   // m * 262144 elements
  #pragma unroll
  for (int e = 0; e < 4; ++e){
    const int j = j0 + e;
    const float x = (e==0) ? v.x : (e==1) ? v.y : (e==2) ? v.z : v.w;
    const int off = ((k>>5)<<14) | ((j>>4)<<9)
                  | ((((j&15) | (((k>>3)&3)<<4)))<<3) | (k&7);
    Wb[base + off] = (__bf16)x;
  }
}

// ---------------------------------------------------------------------------
// 64x64 (per wave) += A[64x512] @ W[512x512] restricted to this wave's cols.
// A from LDS (fragment layout, double-buffered). B from global/L2 in fragment
// order, depth-4 rotating prefetch: b[kt&3] loaded 4 kt (~1240 cyc) ahead,
// consumed under counted vmcnt. Every register-array index is a compile-time
// constant after full unroll (no scratch). No barriers.
// ---------------------------------------------------------------------------
__device__ __forceinline__ void gemm_acc(const __bf16* __restrict__ a_lds,
                                         const __bf16* __restrict__ wb,
                                         f32x4 acc[4][4],
                                         int wv, int lane)
{
  const __bf16* wp = wb + ((wv<<2)<<9) + (lane<<3);  // jt_global = wv*4+jt
  bf16x8 b[4][4];
  bf16x8 a[2][4];
  #pragma unroll
  for (int d = 0; d < 4; ++d)
    #pragma unroll
    for (int jt = 0; jt < 4; ++jt)
      b[d][jt] = *(const bf16x8*)(wp + (d<<14) + (jt<<9));
  #pragma unroll
  for (int rt = 0; rt < 4; ++rt)
    a[0][rt] = *(const bf16x8*)(a_lds + (rt<<9) + (lane<<3));
  #pragma unroll
  for (int kt = 0; kt < 16; ++kt){
    if (kt < 15){
      #pragma unroll
      for (int rt = 0; rt < 4; ++rt)
        a[(kt+1)&1][rt] = *(const bf16x8*)(a_lds + ((kt+1)<<11) + (rt<<9) + (lane<<3));
    }
    #pragma unroll
    for (int jt = 0; jt < 4; ++jt)
      #pragma unroll
      for (int rt = 0; rt < 4; ++rt)
        acc[rt][jt] = __builtin_amdgcn_mfma_f32_16x16x32_bf16(a[kt&1][rt], b[kt&3][jt], acc[rt][jt], 0, 0, 0);
    if (kt + 4 < 16){
      // refill the buffer just consumed with kt+4's fragments
      #pragma unroll
      for (int jt = 0; jt < 4; ++jt)
        b[kt&3][jt] = *(const bf16x8*)(wp + ((kt+4)<<14) + (jt<<9));
    }
  }
}

// ---------------------------------------------------------------------------
// Fused network kernel: 1024 blocks x 512 threads; block owns rows n0..n0+63.
// ---------------------------------------------------------------------------
__global__ __launch_bounds__(512, 2) void fc_fused(
    const float* __restrict__ coords,
    const __bf16* __restrict__ Wb,
    const float* __restrict__ Wu0,  const float* __restrict__ bu0,
    const float* __restrict__ bu,
    const float* __restrict__ bzuu,
    const float* __restrict__ Wzzu_last,
    const float* __restrict__ Wyuu0, const float* __restrict__ byuu0,
    const float* __restrict__ Wyuu,  const float* __restrict__ byuu,
    const float* __restrict__ Wzyu,  const float* __restrict__ Wzyu_last,
    const float* __restrict__ Wzu0,  const float* __restrict__ bzu0,
    const float* __restrict__ bzu,
    const float* __restrict__ Wzu_last, const float* __restrict__ bzu_last,
    const float* __restrict__ p, const float* __restrict__ pu, const float* __restrict__ pzu,
    float* __restrict__ out)
{
  __shared__ __align__(16) __bf16 u_lds [32768];  // 64KB: u[64][512]
  __shared__ __align__(16) __bf16 zz_lds[32768];  // 64KB: z / zz [64][512]
  __shared__ float sp_lds[2][64];                 // s-dot partials (two k-halves)

  const int tid  = threadIdx.x;
  const int lane = tid & 63;
  const int wv   = tid >> 6;        // 0..7
  const int n0   = blockIdx.x << 6;

  const float P  = 10.f * p[0];
  const float PU = 10.f * pu[0];
  const float PZ = 10.f * pzu[0];

  const float y_l = coords[(size_t)(n0 + lane)*4 + 3];   // lane L holds y[row L]

  // -------- layer 0: z0, u0 (D=3 input dots, direct compute) --------
  for (int s = tid; s < 4096; s += 512){
    const int row = s >> 6;
    const int k0  = (s & 63) << 3;
    const float* c = coords + (size_t)(n0 + row)*4;
    const float c0 = c[0], c1 = c[1], c2 = c[2], yy = c[3];
    const float s0 = c0*Wyuu0[0] + c1*Wyuu0[1] + c2*Wyuu0[2] + byuu0[0];
    bf16x8 pu8, pz8;
    #pragma unroll
    for (int e = 0; e < 8; ++e){
      const int k = k0 + e;
      const float uv = c0*Wu0[k]  + c1*Wu0[512+k]  + c2*Wu0[1024+k]  + bu0[k];
      pu8[e] = (__bf16)fmaxf(PU*uv, 0.f);
      const float zv = c0*Wzu0[k] + c1*Wzu0[512+k] + c2*Wzu0[1024+k] + bzu0[k]
                     + yy*s0*Wzyu[k];            // Wzyu[0][:, k]
      pz8[e] = (__bf16)fmaxf(P*zv, 0.f);
    }
    *(bf16x8*)(u_lds  + act_idx(row, k0)) = pu8;
    *(bf16x8*)(zz_lds + act_idx(row, k0)) = pz8;
  }
  __syncthreads();

  f32x4 acc[4][4];

  for (int it = 0; it < 3; ++it){
    const __bf16* w_p1 = Wb + ((size_t)it     << 18);   // Wzuu[it]
    const __bf16* w_zz = Wb + ((size_t)(3+it) << 18);   // Wzzu[it]
    const __bf16* w_zu = Wb + ((size_t)(5+it) << 18);   // Wzu[it]
    const __bf16* w_u  = Wb + ((size_t)(7+it) << 18);   // Wu[it]

    // ---- s-dot: sp[kh][row] = partial of u[row,:] . Wyuu[it] ----
    // wave wv: row-group rt=wv&3, k-half kh=wv>>2; conflict-free frag reads.
    {
      const float* wc = Wyuu + (it<<9);
      const int rt = wv & 3;
      const int kh = wv >> 2;
      float pp = 0.f;
      #pragma unroll
      for (int t = 0; t < 8; ++t){
        const int kt = (kh<<3) + t;
        const int k0 = (kt<<5) + ((lane>>4)<<3);
        bf16x8 v = *(const bf16x8*)(u_lds + (kt<<11) + (rt<<9) + (lane<<3));
        const float4 w0 = *(const float4*)(wc + k0);
        const float4 w1 = *(const float4*)(wc + k0 + 4);
        pp += (float)v[0]*w0.x + (float)v[1]*w0.y + (float)v[2]*w0.z + (float)v[3]*w0.w
            + (float)v[4]*w1.x + (float)v[5]*w1.y + (float)v[6]*w1.z + (float)v[7]*w1.w;
      }
      pp += __shfl_xor(pp, 16);
      pp += __shfl_xor(pp, 32);
      if (lane < 16) sp_lds[kh][(rt<<4) + lane] = pp;
    }

    // ---- phase 1: t = u @ Wzuu[it];  zz = z * relu(PZ*(t + bzuu[it])) ----
    #pragma unroll
    for (int rt = 0; rt < 4; ++rt)
      #pragma unroll
      for (int jt = 0; jt < 4; ++jt)
        acc[rt][jt] = (f32x4){0.f,0.f,0.f,0.f};
    gemm_acc(u_lds, w_p1, acc, wv, lane);
    #pragma unroll
    for (int jt = 0; jt < 4; ++jt){
      const int col = (wv<<6) + (jt<<4) + (lane & 15);
      const float bz = bzuu[(it<<9) + col];
      #pragma unroll
      for (int rt = 0; rt < 4; ++rt){
        #pragma unroll
        for (int rr = 0; rr < 4; ++rr){
          const int row = (rt<<4) + ((lane>>4)<<2) + rr;
          const int idx = act_idx(row, col);
          const float zold = (float)zz_lds[idx];    // element owned by this thread
          const float t    = acc[rt][jt][rr] + bz;
          zz_lds[idx] = (__bf16)(zold * fmaxf(PZ*t, 0.f));
        }
      }
    }
    __syncthreads();   // zz + sp fully written before reads

    if (it < 2){
      // ---- phase 2a: z = relu(P*(zz@Wzzu + u@Wzu + bzu + y*s*Wzyu[it+1])) ----
      #pragma unroll
      for (int rt = 0; rt < 4; ++rt)
        #pragma unroll
        for (int jt = 0; jt < 4; ++jt)
          acc[rt][jt] = (f32x4){0.f,0.f,0.f,0.f};
      gemm_acc(zz_lds, w_zz, acc, wv, lane);
      gemm_acc(u_lds,  w_zu, acc, wv, lane);
      __syncthreads();   // all waves done reading zz before epilogue overwrites it

      const float by_it = byuu[it];
      float ysr[4][4];
      #pragma unroll
      for (int rt = 0; rt < 4; ++rt)
        #pragma unroll
        for (int rr = 0; rr < 4; ++rr){
          const int row = (rt<<4) + ((lane>>4)<<2) + rr;
          ysr[rt][rr] = __shfl(y_l, row) * (sp_lds[0][row] + sp_lds[1][row] + by_it);
        }
      #pragma unroll
      for (int jt = 0; jt < 4; ++jt){
        const int col = (wv<<6) + (jt<<4) + (lane & 15);
        const float bz  = bzu[(it<<9) + col];
        const float wzy = Wzyu[((it+1)<<9) + col];
        #pragma unroll
        for (int rt = 0; rt < 4; ++rt){
          #pragma unroll
          for (int rr = 0; rr < 4; ++rr){
            const int row = (rt<<4) + ((lane>>4)<<2) + rr;
            const float zn = acc[rt][jt][rr] + bz + ysr[rt][rr]*wzy;
            zz_lds[act_idx(row, col)] = (__bf16)fmaxf(P*zn, 0.f);
          }
        }
      }

      // ---- phase 2b: u = relu(PU*(u @ Wu[it] + bu[it])) ----
      #pragma unroll
      for (int rt = 0; rt < 4; ++rt)
        #pragma unroll
        for (int jt = 0; jt < 4; ++jt)
          acc[rt][jt] = (f32x4){0.f,0.f,0.f,0.f};
      gemm_acc(u_lds, w_u, acc, wv, lane);
      __syncthreads();   // all waves done reading u before epilogue overwrites it
      #pragma unroll
      for (int jt = 0; jt < 4; ++jt){
        const int col = (wv<<6) + (jt<<4) + (lane & 15);
        const float bb = bu[(it<<9) + col];
        #pragma unroll
        for (int rt = 0; rt < 4; ++rt){
          #pragma unroll
          for (int rr = 0; rr < 4; ++rr){
            const int row = (rt<<4) + ((lane>>4)<<2) + rr;
            u_lds[act_idx(row, col)] = (__bf16)fmaxf(PU*(acc[rt][jt][rr] + bb), 0.f);
          }
        }
      }
      __syncthreads();   // u/z writes visible before next iteration's reads
    } else {
      // ---- final: out = zz.Wzzu_last + u.Wzu_last + bzu_last + y*s*Wzyu_last ----
      const int row = tid >> 3;     // 0..63
      const int q   = tid & 7;
      float av = 0.f, au = 0.f;
      for (int kb = q*8; kb < q*8 + 8; ++kb){
        const int k0 = kb << 3;
        bf16x8 vz = *(const bf16x8*)(zz_lds + act_idx(row, k0));
        bf16x8 vu = *(const bf16x8*)(u_lds  + act_idx(row, k0));
        #pragma unroll
        for (int e = 0; e < 8; ++e){
          av += (float)vz[e] * Wzzu_last[k0+e];
          au += (float)vu[e] * Wzu_last [k0+e];
        }
      }
      float tot = av + au;
      tot += __shfl_xor(tot, 1);
      tot += __shfl_xor(tot, 2);
      tot += __shfl_xor(tot, 4);
      const float sv = sp_lds[0][row] + sp_lds[1][row] + byuu[2];
      const float yv = __shfl(y_l, row & 63);
      if (q == 0)
        out[n0 + row] = tot + bzu_last[0] + yv*sv*Wzyu_last[0];
    }
  }
}

// ---------------------------------------------------------------------------
extern "C" void kernel_launch(void* const* d_in, const int* in_sizes, int n_in,
                              void* d_out, int out_size, void* d_ws, size_t ws_size,
                              hipStream_t stream)
{
  const float* coords    = (const float*)d_in[0];
  const float* Wu0       = (const float*)d_in[1];
  const float* bu0       = (const float*)d_in[2];
  const float* Wu        = (const float*)d_in[3];
  const float* bu        = (const float*)d_in[4];
  const float* Wzuu      = (const float*)d_in[5];
  const float* bzuu      = (const float*)d_in[6];
  const float* Wzzu      = (const float*)d_in[7];
  const float* Wzzu_last = (const float*)d_in[8];
  const float* Wyuu0     = (const float*)d_in[9];
  const float* byuu0     = (const float*)d_in[10];
  const float* Wyuu      = (const float*)d_in[11];
  const float* byuu      = (const float*)d_in[12];
  const float* Wzyu      = (const float*)d_in[13];
  const float* Wzyu_last = (const float*)d_in[14];
  const float* Wzu0      = (const float*)d_in[15];
  const float* bzu0      = (const float*)d_in[16];
  const float* Wzu       = (const float*)d_in[17];
  const float* bzu       = (const float*)d_in[18];
  const float* Wzu_last  = (const float*)d_in[19];
  const float* bzu_last  = (const float*)d_in[20];
  const float* p         = (const float*)d_in[21];
  const float* pu        = (const float*)d_in[22];
  const float* pzu       = (const float*)d_in[23];

  __bf16* Wb = (__bf16*)d_ws;   // 9 * 512KB = 4.5 MB bf16 fragment-block weights

  prep_weights<<<2304, 256, 0, stream>>>(Wzuu, Wzzu, Wzu, Wu, Wb);

  fc_fused<<<1024, 512, 0, stream>>>(
      coords, Wb,
      Wu0, bu0, bu, bzuu, Wzzu_last,
      Wyuu0, byuu0, Wyuu, byuu, Wzyu, Wzyu_last,
      Wzu0, bzu0, bzu, Wzu_last, bzu_last,
      p, pu, pzu,
      (float*)d_out);
}